// Round 15
// baseline (83.064 us; speedup 1.0000x reference)
//
#include <hip/hip_runtime.h>
#include <math.h>

// Problem constants (match reference)
#define Bdim 8
#define Lq   256
#define Hd   128

static constexpr float kNEG = -4294967295.0f;           // -(2^32)+1 as f32
static constexpr float kScale = 0.17677669529663687f;   // 1/sqrt(32)
static constexpr float kUni = 0.00390625f;              // 1/256 (exact)

typedef float f32x4 __attribute__((ext_vector_type(4)));

// ---------------------------------------------------------------------------
// prep: blocks 0-11 transpose Wq/Wk/Wv (64x64 LDS tiles, coalesced both ways);
//       block 12 normalizes the bool time_mask (u8 vs i32 auto-detect).
// ---------------------------------------------------------------------------
__global__ __launch_bounds__(256) void prep_kernel(
    const float* __restrict__ Wq, const float* __restrict__ Wk,
    const float* __restrict__ Wv, const unsigned char* __restrict__ raw,
    float* __restrict__ Wt, int* __restrict__ outmask)
{
    const int blk = blockIdx.x;
    if (blk < 12) {
        __shared__ float tile[64][65];
        const int mi = blk >> 2;
        const float* W = (mi == 0) ? Wq : (mi == 1) ? Wk : Wv;
        float* WT = Wt + mi * (Hd * Hd);
        const int ti = blk & 3;
        const int r0 = (ti >> 1) * 64, c0 = (ti & 1) * 64;
        #pragma unroll
        for (int k = 0; k < 16; ++k) {
            const int e = threadIdx.x + k * 256;
            const int r = e >> 6, c = e & 63;
            tile[r][c] = W[(r0 + r) * Hd + (c0 + c)];
        }
        __syncthreads();
        #pragma unroll
        for (int k = 0; k < 16; ++k) {
            const int e = threadIdx.x + k * 256;
            const int r = e >> 6, c = e & 63;
            WT[(c0 + r) * Hd + (r0 + c)] = tile[c][r];
        }
    } else {
        __shared__ int cnt;
        if (threadIdx.x == 0) cnt = 0;
        __syncthreads();
        const int n = Bdim * Lq;
        for (int i = threadIdx.x; i < n; i += 256)
            if ((i & 3) && raw[i]) atomicAdd(&cnt, 1);
        __syncthreads();
        const bool is_u8 = (cnt > 0);
        const int* raw32 = (const int*)raw;
        for (int i = threadIdx.x; i < n; i += 256) {
            const int v = is_u8 ? (int)raw[i] : raw32[i];
            outmask[i] = (v != 0) ? 1 : 0;
        }
    }
}

// ---------------------------------------------------------------------------
// Projections (fused abs_pos adds), W pre-transposed so loads are coalesced.
// 512 threads (8 waves/block): o = tid&127, rh = tid>>7, 2 rows/thread.
// ---------------------------------------------------------------------------
__global__ __launch_bounds__(512) void proj_kernel(
    const float* __restrict__ queries, const float* __restrict__ keys,
    const float* __restrict__ absK, const float* __restrict__ absV,
    const float* __restrict__ Wt,
    const float* __restrict__ bq, const float* __restrict__ bk,
    const float* __restrict__ bv,
    float* __restrict__ Qb, float* __restrict__ Kb, float* __restrict__ Vb)
{
    constexpr int R = 8;
    __shared__ float xq[R][Hd];
    __shared__ float xk[R][Hd];
    const int row0 = blockIdx.x * R;
    const int tid = threadIdx.x;
    #pragma unroll
    for (int k = 0; k < 2; ++k) {
        const int e = tid + k * 512;
        const int r = e >> 7, c = e & 127;
        xq[r][c] = queries[(row0 + r) * Hd + c];
        xk[r][c] = keys[(row0 + r) * Hd + c];
    }
    __syncthreads();

    const int o = tid & 127, rh = tid >> 7;
    const int r0 = rh * 2, r1 = rh * 2 + 1;
    const float* __restrict__ Wtq = Wt;
    const float* __restrict__ Wtk = Wt + Hd * Hd;
    const float* __restrict__ Wtv = Wt + 2 * Hd * Hd;

    float qa0 = bq[o], qa1 = qa0;
    float ka0 = bk[o] + absK[(row0 + r0) * Hd + o];
    float ka1 = bk[o] + absK[(row0 + r1) * Hd + o];
    float va0 = bv[o] + absV[(row0 + r0) * Hd + o];
    float va1 = bv[o] + absV[(row0 + r1) * Hd + o];

    #pragma unroll 4
    for (int i = 0; i < Hd; ++i) {
        const float wq = Wtq[i * Hd + o];
        const float wk = Wtk[i * Hd + o];
        const float wv = Wtv[i * Hd + o];
        const float x0 = xq[r0][i], x1 = xq[r1][i];
        const float y0 = xk[r0][i], y1 = xk[r1][i];
        qa0 += x0 * wq; qa1 += x1 * wq;
        ka0 += y0 * wk; ka1 += y1 * wk;
        va0 += y0 * wv; va1 += y1 * wv;
    }
    Qb[(row0 + r0) * Hd + o] = qa0;  Qb[(row0 + r1) * Hd + o] = qa1;
    Kb[(row0 + r0) * Hd + o] = ka0;  Kb[(row0 + r1) * Hd + o] = ka1;
    Vb[(row0 + r0) * Hd + o] = va0;  Vb[(row0 + r1) * Hd + o] = va1;
}

// ---------------------------------------------------------------------------
// Fused attention v12: SINGLE-l waves for minimal VGPR -> max occupancy.
// 2048 blocks = (b:8) x (hp:2) x (p:128); 4 waves/block:
//   head = hp*2 + (w&1);  li = (w>>1) ^ ((p>>4)&1);  l = li ? 255-p : p.
// Block work = (p+1)+(256-p) x2 heads = constant; the (p>>4)&1 flip makes
// each SIMD alternate short/long-l waves across resident block generations
// (p steps by 16 per round-robin generation) -> per-SIMD balance.
// K/V read per-wave from cache (r11/r12/r14 proved K/V traffic is free).
// Scores+softmax in registers (s[16], ~64-80 VGPR -> 24-32 waves/CU);
// zero LDS, zero barriers; masked rows exact uniform 1/256.
// Lane map: m_off=(lane>>2)&15, cg=lane&3, ch=h*32+cg*8.
// ---------------------------------------------------------------------------
__global__ __launch_bounds__(256, 6) void attn_kernel(
    const float* __restrict__ Qb, const float* __restrict__ Kb,
    const float* __restrict__ Vb,
    const float* __restrict__ tK, const float* __restrict__ tV,
    const int* __restrict__ tmask, float* __restrict__ out)
{
    const int bid = blockIdx.x;
    const int b  = bid & 7;
    const int hp = (bid >> 3) & 1;
    const int p  = bid >> 4;                // 0..127

    const int tid = threadIdx.x;
    const int w = tid >> 6;
    const int lane = tid & 63;
    const int h = hp * 2 + (w & 1);
    const int li = ((w >> 1) ^ ((p >> 4) & 1)) & 1;
    const int l = li ? (255 - p) : p;
    const int m_off = (lane >> 2) & 15;
    const int cg = lane & 3;
    const int ch = h * 32 + cg * 8;

    // Q row (pre-scaled by 1/sqrt(D))
    const float* qb = Qb + ((size_t)b * Lq + l) * Hd + ch;
    f32x4 q0 = *(const f32x4*)qb * kScale;
    f32x4 q1 = *(const f32x4*)(qb + 4) * kScale;

    const bool mk = (tmask[b * Lq + l] != 0);
    const int ntc = (l >> 4) + 1;           // causal tiles
    const int n1 = mk ? 0 : ntc;            // phase-1 bound
    const int n2 = mk ? 16 : ntc;           // phase-2 bound

    const float* kpt = Kb + (size_t)b * Lq * Hd + m_off * Hd + ch;
    const float* vpt = Vb + (size_t)b * Lq * Hd + m_off * Hd + ch;
    const float* tp  = tK + (((size_t)b * Lq + l) * Lq + m_off) * Hd + ch;
    const float* up  = tV + (((size_t)b * Lq + l) * Lq + m_off) * Hd + ch;

    // ---- phase 1: scores in registers ----
    float s[16];
    #pragma unroll
    for (int t = 0; t < 16; ++t) s[t] = kNEG;

    #pragma unroll
    for (int t = 0; t < 16; ++t) {
        if (t < n1) {
            const f32x4 sa = *(const f32x4*)(kpt + t * 2048)
                           + *(const f32x4*)(tp + t * 2048);
            const f32x4 sb = *(const f32x4*)(kpt + t * 2048 + 4)
                           + *(const f32x4*)(tp + t * 2048 + 4);
            float pp = q0.x*sa.x + q0.y*sa.y + q0.z*sa.z + q0.w*sa.w
                     + q1.x*sb.x + q1.y*sb.y + q1.z*sb.z + q1.w*sb.w;
            pp += __shfl_xor(pp, 1);
            pp += __shfl_xor(pp, 2);
            const int m = t * 16 + m_off;
            s[t] = (m <= l) ? pp : kNEG;
        }
    }

    // ---- softmax in registers (reduce over m_off = lane bits 2..5) ----
    if (!mk) {
        float mx = s[0];
        #pragma unroll
        for (int t = 1; t < 16; ++t) mx = fmaxf(mx, s[t]);
        #pragma unroll
        for (int d = 4; d < 64; d <<= 1) mx = fmaxf(mx, __shfl_xor(mx, d));
        float sum = 0.f;
        #pragma unroll
        for (int t = 0; t < 16; ++t) { s[t] = expf(s[t] - mx); sum += s[t]; }
        #pragma unroll
        for (int d = 4; d < 64; d <<= 1) sum += __shfl_xor(sum, d);
        const float inv = 1.0f / sum;
        #pragma unroll
        for (int t = 0; t < 16; ++t) s[t] *= inv;
    } else {
        #pragma unroll
        for (int t = 0; t < 16; ++t) s[t] = kUni;
    }

    // ---- phase 2: output (weights lane-aligned with V rows) ----
    f32x4 a0 = {0,0,0,0}, a1 = {0,0,0,0};
    #pragma unroll
    for (int t = 0; t < 16; ++t) {
        if (t < n2) {
            const f32x4 va = *(const f32x4*)(vpt + t * 2048)
                           + *(const f32x4*)(up + t * 2048);
            const f32x4 vb = *(const f32x4*)(vpt + t * 2048 + 4)
                           + *(const f32x4*)(up + t * 2048 + 4);
            a0 += s[t] * va;
            a1 += s[t] * vb;
        }
    }
    // reduce over the 16 m_off lane-groups (lane bits 2..5)
    #pragma unroll
    for (int d = 4; d < 64; d <<= 1) {
        a0.x += __shfl_xor(a0.x, d); a0.y += __shfl_xor(a0.y, d);
        a0.z += __shfl_xor(a0.z, d); a0.w += __shfl_xor(a0.w, d);
        a1.x += __shfl_xor(a1.x, d); a1.y += __shfl_xor(a1.y, d);
        a1.z += __shfl_xor(a1.z, d); a1.w += __shfl_xor(a1.w, d);
    }
    if (m_off == 0) {
        float* o = out + ((size_t)b * Lq + l) * Hd + ch;
        *(f32x4*)o       = a0;
        *(f32x4*)(o + 4) = a1;
    }
}

// ---------------------------------------------------------------------------
extern "C" void kernel_launch(void* const* d_in, const int* in_sizes, int n_in,
                              void* d_out, int out_size, void* d_ws, size_t ws_size,
                              hipStream_t stream) {
    const float* queries = (const float*)d_in[0];
    const float* keys    = (const float*)d_in[1];
    const float* tK      = (const float*)d_in[2];
    const float* tV      = (const float*)d_in[3];
    const float* absK    = (const float*)d_in[4];
    const float* absV    = (const float*)d_in[5];
    const float* Wq      = (const float*)d_in[6];
    const float* bq      = (const float*)d_in[7];
    const float* Wk      = (const float*)d_in[8];
    const float* bk      = (const float*)d_in[9];
    const float* Wv      = (const float*)d_in[10];
    const float* bv      = (const float*)d_in[11];
    const unsigned char* tmask_raw = (const unsigned char*)d_in[12];
    // d_in[13] (attn_mask) is deterministic triu(k=1) -> handled in-kernel.

    float* outp = (float*)d_out;

    const int rows = Bdim * Lq;                    // 2048
    float* Qb = (float*)d_ws;                      // 1 MB
    float* Kb = Qb + (size_t)rows * Hd;            // 1 MB
    float* Vb = Kb + (size_t)rows * Hd;            // 1 MB
    int* tmask = (int*)(Vb + (size_t)rows * Hd);   // 8 KB
    float* Wt = (float*)(tmask + rows);            // 192 KB (3 transposed W)

    prep_kernel<<<13, 256, 0, stream>>>(Wq, Wk, Wv, tmask_raw, Wt, tmask);
    proj_kernel<<<rows / 8, 512, 0, stream>>>(queries, keys, absK, absV, Wt,
                                              bq, bk, bv, Qb, Kb, Vb);
    attn_kernel<<<2048, 256, 0, stream>>>(Qb, Kb, Vb, tK, tV, tmask, outp);
}

// Round 16
// 77.837 us; speedup vs baseline: 1.0672x; 1.0672x over previous
//
#include <hip/hip_runtime.h>
#include <math.h>

// Problem constants (match reference)
#define Bdim 8
#define Lq   256
#define Hd   128

static constexpr float kNEG = -4294967295.0f;           // -(2^32)+1 as f32
static constexpr float kScale = 0.17677669529663687f;   // 1/sqrt(32)
static constexpr float kUni = 0.00390625f;              // 1/256 (exact)

// ---------------------------------------------------------------------------
// prep: blocks 0-11 transpose Wq/Wk/Wv (64x64 LDS tiles, coalesced both ways);
//       block 12 normalizes the bool time_mask (u8 vs i32 auto-detect).
// ---------------------------------------------------------------------------
__global__ __launch_bounds__(256) void prep_kernel(
    const float* __restrict__ Wq, const float* __restrict__ Wk,
    const float* __restrict__ Wv, const unsigned char* __restrict__ raw,
    float* __restrict__ Wt, int* __restrict__ outmask)
{
    const int blk = blockIdx.x;
    if (blk < 12) {
        __shared__ float tile[64][65];
        const int mi = blk >> 2;
        const float* W = (mi == 0) ? Wq : (mi == 1) ? Wk : Wv;
        float* WT = Wt + mi * (Hd * Hd);
        const int ti = blk & 3;
        const int r0 = (ti >> 1) * 64, c0 = (ti & 1) * 64;
        #pragma unroll
        for (int k = 0; k < 16; ++k) {
            const int e = threadIdx.x + k * 256;
            const int r = e >> 6, c = e & 63;
            tile[r][c] = W[(r0 + r) * Hd + (c0 + c)];
        }
        __syncthreads();
        #pragma unroll
        for (int k = 0; k < 16; ++k) {
            const int e = threadIdx.x + k * 256;
            const int r = e >> 6, c = e & 63;
            WT[(c0 + r) * Hd + (r0 + c)] = tile[c][r];
        }
    } else {
        __shared__ int cnt;
        if (threadIdx.x == 0) cnt = 0;
        __syncthreads();
        const int n = Bdim * Lq;
        for (int i = threadIdx.x; i < n; i += 256)
            if ((i & 3) && raw[i]) atomicAdd(&cnt, 1);
        __syncthreads();
        const bool is_u8 = (cnt > 0);
        const int* raw32 = (const int*)raw;
        for (int i = threadIdx.x; i < n; i += 256) {
            const int v = is_u8 ? (int)raw[i] : raw32[i];
            outmask[i] = (v != 0) ? 1 : 0;
        }
    }
}

// ---------------------------------------------------------------------------
// Projections (fused abs_pos adds), W pre-transposed so loads are coalesced.
// 512 threads (8 waves/block): o = tid&127, rh = tid>>7, 2 rows/thread.
// ---------------------------------------------------------------------------
__global__ __launch_bounds__(512) void proj_kernel(
    const float* __restrict__ queries, const float* __restrict__ keys,
    const float* __restrict__ absK, const float* __restrict__ absV,
    const float* __restrict__ Wt,
    const float* __restrict__ bq, const float* __restrict__ bk,
    const float* __restrict__ bv,
    float* __restrict__ Qb, float* __restrict__ Kb, float* __restrict__ Vb)
{
    constexpr int R = 8;
    __shared__ float xq[R][Hd];
    __shared__ float xk[R][Hd];
    const int row0 = blockIdx.x * R;
    const int tid = threadIdx.x;
    #pragma unroll
    for (int k = 0; k < 2; ++k) {
        const int e = tid + k * 512;
        const int r = e >> 7, c = e & 127;
        xq[r][c] = queries[(row0 + r) * Hd + c];
        xk[r][c] = keys[(row0 + r) * Hd + c];
    }
    __syncthreads();

    const int o = tid & 127, rh = tid >> 7;
    const int r0 = rh * 2, r1 = rh * 2 + 1;
    const float* __restrict__ Wtq = Wt;
    const float* __restrict__ Wtk = Wt + Hd * Hd;
    const float* __restrict__ Wtv = Wt + 2 * Hd * Hd;

    float qa0 = bq[o], qa1 = qa0;
    float ka0 = bk[o] + absK[(row0 + r0) * Hd + o];
    float ka1 = bk[o] + absK[(row0 + r1) * Hd + o];
    float va0 = bv[o] + absV[(row0 + r0) * Hd + o];
    float va1 = bv[o] + absV[(row0 + r1) * Hd + o];

    #pragma unroll 4
    for (int i = 0; i < Hd; ++i) {
        const float wq = Wtq[i * Hd + o];
        const float wk = Wtk[i * Hd + o];
        const float wv = Wtv[i * Hd + o];
        const float x0 = xq[r0][i], x1 = xq[r1][i];
        const float y0 = xk[r0][i], y1 = xk[r1][i];
        qa0 += x0 * wq; qa1 += x1 * wq;
        ka0 += y0 * wk; ka1 += y1 * wk;
        va0 += y0 * wv; va1 += y1 * wv;
    }
    Qb[(row0 + r0) * Hd + o] = qa0;  Qb[(row0 + r1) * Hd + o] = qa1;
    Kb[(row0 + r0) * Hd + o] = ka0;  Kb[(row0 + r1) * Hd + o] = ka1;
    Vb[(row0 + r0) * Hd + o] = va0;  Vb[(row0 + r1) * Hd + o] = va1;
}

// ---------------------------------------------------------------------------
// Fused attention v5 (round-8 optimum, resubmitted verbatim):
// 1024 blocks = (b:8) x (hp:2) x (j:64). 4 waves/block, each independent:
// wave w -> head hp*2+(w&1), COMPLEMENTARY l-pair p = j*2+(w>>1), l0 = p,
// l1 = 255-p. Per-wave work = (p+1)+(256-p) = 257 rows = CONSTANT -> perfect
// load balance on every CU regardless of dispatch policy. K/V tiles loaded
// to registers once per tile, reused across both l's. Scores+softmax fully
// in registers (static 16-tile unroll); zero LDS, zero barriers. Masked
// rows: exact uniform 1/256 path.
// Lane map: m_off=(tid>>2)&15 (m within tile), cg=tid&3 (8-ch group of head).
// ---------------------------------------------------------------------------
__global__ __launch_bounds__(256) void attn_kernel(
    const float* __restrict__ Qb, const float* __restrict__ Kb,
    const float* __restrict__ Vb,
    const float* __restrict__ tK, const float* __restrict__ tV,
    const int* __restrict__ tmask, float* __restrict__ out)
{
    const int bid = blockIdx.x;
    const int b  = bid & 7;
    const int hp = (bid >> 3) & 1;
    const int j  = bid >> 4;                // 0..63

    const int tid = threadIdx.x;
    const int w = tid >> 6;
    const int h = hp * 2 + (w & 1);
    const int p = j * 2 + (w >> 1);         // 0..127
    const int l0 = p;
    const int l1 = 255 - p;
    const int m_off = (tid >> 2) & 15;
    const int cg = tid & 3;
    const int ch = h * 32 + cg * 8;

    // Q rows (pre-scaled by 1/sqrt(D))
    const float* q0b = Qb + ((size_t)b * Lq + l0) * Hd + ch;
    const float* q1b = Qb + ((size_t)b * Lq + l1) * Hd + ch;
    float4 q00 = ((const float4*)q0b)[0], q01 = ((const float4*)q0b)[1];
    float4 q10 = ((const float4*)q1b)[0], q11 = ((const float4*)q1b)[1];
    q00.x*=kScale; q00.y*=kScale; q00.z*=kScale; q00.w*=kScale;
    q01.x*=kScale; q01.y*=kScale; q01.z*=kScale; q01.w*=kScale;
    q10.x*=kScale; q10.y*=kScale; q10.z*=kScale; q10.w*=kScale;
    q11.x*=kScale; q11.y*=kScale; q11.z*=kScale; q11.w*=kScale;

    const bool mk0 = (tmask[b * Lq + l0] != 0);
    const bool mk1 = (tmask[b * Lq + l1] != 0);
    const int ntc0 = (l0 >> 4) + 1, ntc1 = (l1 >> 4) + 1;   // causal tiles
    const int n10 = mk0 ? 0 : ntc0, n11 = mk1 ? 0 : ntc1;   // phase-1 bounds
    const int NT1 = (n10 > n11) ? n10 : n11;
    const int n20 = mk0 ? 16 : ntc0, n21 = mk1 ? 16 : ntc1; // phase-2 bounds
    const int NT2 = (n20 > n21) ? n20 : n21;

    const float* kpt = Kb + (size_t)b * Lq * Hd + m_off * Hd + ch;
    const float* vpt = Vb + (size_t)b * Lq * Hd + m_off * Hd + ch;
    const float* t0p = tK + (((size_t)b * Lq + l0) * Lq + m_off) * Hd + ch;
    const float* t1p = tK + (((size_t)b * Lq + l1) * Lq + m_off) * Hd + ch;
    const float* u0p = tV + (((size_t)b * Lq + l0) * Lq + m_off) * Hd + ch;
    const float* u1p = tV + (((size_t)b * Lq + l1) * Lq + m_off) * Hd + ch;

    // ---- phase 1: scores in registers (K-tile regs shared by both l's) ----
    float s0[16], s1[16];
    #pragma unroll
    for (int t = 0; t < 16; ++t) { s0[t] = kNEG; s1[t] = kNEG; }

    #pragma unroll
    for (int t = 0; t < 16; ++t) {
        if (t < NT1) {
            const float4 ka = *(const float4*)(kpt + t * 2048);
            const float4 kb = *(const float4*)(kpt + t * 2048 + 4);
            const int m = t * 16 + m_off;
            if (t < n10) {
                const float4 ta = *(const float4*)(t0p + t * 2048);
                const float4 tb = *(const float4*)(t0p + t * 2048 + 4);
                float pp = q00.x*(ka.x+ta.x) + q00.y*(ka.y+ta.y)
                         + q00.z*(ka.z+ta.z) + q00.w*(ka.w+ta.w)
                         + q01.x*(kb.x+tb.x) + q01.y*(kb.y+tb.y)
                         + q01.z*(kb.z+tb.z) + q01.w*(kb.w+tb.w);
                pp += __shfl_xor(pp, 1);
                pp += __shfl_xor(pp, 2);
                s0[t] = (m <= l0) ? pp : kNEG;
            }
            if (t < n11) {
                const float4 ta = *(const float4*)(t1p + t * 2048);
                const float4 tb = *(const float4*)(t1p + t * 2048 + 4);
                float pp = q10.x*(ka.x+ta.x) + q10.y*(ka.y+ta.y)
                         + q10.z*(ka.z+ta.z) + q10.w*(ka.w+ta.w)
                         + q11.x*(kb.x+tb.x) + q11.y*(kb.y+tb.y)
                         + q11.z*(kb.z+tb.z) + q11.w*(kb.w+tb.w);
                pp += __shfl_xor(pp, 1);
                pp += __shfl_xor(pp, 2);
                s1[t] = (m <= l1) ? pp : kNEG;
            }
        }
    }

    // ---- softmax, fully in registers (reduce over m_off = lane bits 2..5) --
    if (!mk0) {
        float mx = s0[0];
        #pragma unroll
        for (int t = 1; t < 16; ++t) mx = fmaxf(mx, s0[t]);
        #pragma unroll
        for (int d = 4; d < 64; d <<= 1) mx = fmaxf(mx, __shfl_xor(mx, d));
        float sum = 0.f;
        #pragma unroll
        for (int t = 0; t < 16; ++t) { s0[t] = expf(s0[t] - mx); sum += s0[t]; }
        #pragma unroll
        for (int d = 4; d < 64; d <<= 1) sum += __shfl_xor(sum, d);
        const float inv = 1.0f / sum;
        #pragma unroll
        for (int t = 0; t < 16; ++t) s0[t] *= inv;
    } else {
        #pragma unroll
        for (int t = 0; t < 16; ++t) s0[t] = kUni;
    }
    if (!mk1) {
        float mx = s1[0];
        #pragma unroll
        for (int t = 1; t < 16; ++t) mx = fmaxf(mx, s1[t]);
        #pragma unroll
        for (int d = 4; d < 64; d <<= 1) mx = fmaxf(mx, __shfl_xor(mx, d));
        float sum = 0.f;
        #pragma unroll
        for (int t = 0; t < 16; ++t) { s1[t] = expf(s1[t] - mx); sum += s1[t]; }
        #pragma unroll
        for (int d = 4; d < 64; d <<= 1) sum += __shfl_xor(sum, d);
        const float inv = 1.0f / sum;
        #pragma unroll
        for (int t = 0; t < 16; ++t) s1[t] *= inv;
    } else {
        #pragma unroll
        for (int t = 0; t < 16; ++t) s1[t] = kUni;
    }

    // ---- phase 2: output (V-tile regs shared by both l's; weights are
    //      already lane-aligned with V rows -> no shuffles in the loop) ----
    float4 a00 = {0,0,0,0}, a01 = {0,0,0,0};
    float4 a10 = {0,0,0,0}, a11 = {0,0,0,0};
    #pragma unroll
    for (int t = 0; t < 16; ++t) {
        if (t < NT2) {
            const float4 va = *(const float4*)(vpt + t * 2048);
            const float4 vb = *(const float4*)(vpt + t * 2048 + 4);
            if (t < n20) {
                const float4 ta = *(const float4*)(u0p + t * 2048);
                const float4 tb = *(const float4*)(u0p + t * 2048 + 4);
                const float aw = s0[t];
                a00.x += aw*(va.x+ta.x); a00.y += aw*(va.y+ta.y);
                a00.z += aw*(va.z+ta.z); a00.w += aw*(va.w+ta.w);
                a01.x += aw*(vb.x+tb.x); a01.y += aw*(vb.y+tb.y);
                a01.z += aw*(vb.z+tb.z); a01.w += aw*(vb.w+tb.w);
            }
            if (t < n21) {
                const float4 ta = *(const float4*)(u1p + t * 2048);
                const float4 tb = *(const float4*)(u1p + t * 2048 + 4);
                const float aw = s1[t];
                a10.x += aw*(va.x+ta.x); a10.y += aw*(va.y+ta.y);
                a10.z += aw*(va.z+ta.z); a10.w += aw*(va.w+ta.w);
                a11.x += aw*(vb.x+tb.x); a11.y += aw*(vb.y+tb.y);
                a11.z += aw*(vb.z+tb.z); a11.w += aw*(vb.w+tb.w);
            }
        }
    }
    // reduce over the 16 m_off lane-groups
    #pragma unroll
    for (int d = 4; d < 64; d <<= 1) {
        a00.x += __shfl_xor(a00.x, d); a00.y += __shfl_xor(a00.y, d);
        a00.z += __shfl_xor(a00.z, d); a00.w += __shfl_xor(a00.w, d);
        a01.x += __shfl_xor(a01.x, d); a01.y += __shfl_xor(a01.y, d);
        a01.z += __shfl_xor(a01.z, d); a01.w += __shfl_xor(a01.w, d);
        a10.x += __shfl_xor(a10.x, d); a10.y += __shfl_xor(a10.y, d);
        a10.z += __shfl_xor(a10.z, d); a10.w += __shfl_xor(a10.w, d);
        a11.x += __shfl_xor(a11.x, d); a11.y += __shfl_xor(a11.y, d);
        a11.z += __shfl_xor(a11.z, d); a11.w += __shfl_xor(a11.w, d);
    }
    if (m_off == 0) {
        float* o0 = out + ((size_t)b * Lq + l0) * Hd + ch;
        ((float4*)o0)[0] = a00; ((float4*)o0)[1] = a01;
        float* o1 = out + ((size_t)b * Lq + l1) * Hd + ch;
        ((float4*)o1)[0] = a10; ((float4*)o1)[1] = a11;
    }
}

// ---------------------------------------------------------------------------
extern "C" void kernel_launch(void* const* d_in, const int* in_sizes, int n_in,
                              void* d_out, int out_size, void* d_ws, size_t ws_size,
                              hipStream_t stream) {
    const float* queries = (const float*)d_in[0];
    const float* keys    = (const float*)d_in[1];
    const float* tK      = (const float*)d_in[2];
    const float* tV      = (const float*)d_in[3];
    const float* absK    = (const float*)d_in[4];
    const float* absV    = (const float*)d_in[5];
    const float* Wq      = (const float*)d_in[6];
    const float* bq      = (const float*)d_in[7];
    const float* Wk      = (const float*)d_in[8];
    const float* bk      = (const float*)d_in[9];
    const float* Wv      = (const float*)d_in[10];
    const float* bv      = (const float*)d_in[11];
    const unsigned char* tmask_raw = (const unsigned char*)d_in[12];
    // d_in[13] (attn_mask) is deterministic triu(k=1) -> handled in-kernel.

    float* outp = (float*)d_out;

    const int rows = Bdim * Lq;                    // 2048
    float* Qb = (float*)d_ws;                      // 1 MB
    float* Kb = Qb + (size_t)rows * Hd;            // 1 MB
    float* Vb = Kb + (size_t)rows * Hd;            // 1 MB
    int* tmask = (int*)(Vb + (size_t)rows * Hd);   // 8 KB
    float* Wt = (float*)(tmask + rows);            // 192 KB (3 transposed W)

    prep_kernel<<<13, 256, 0, stream>>>(Wq, Wk, Wv, tmask_raw, Wt, tmask);
    proj_kernel<<<rows / 8, 512, 0, stream>>>(queries, keys, absK, absV, Wt,
                                              bq, bk, bv, Qb, Kb, Vb);
    attn_kernel<<<1024, 256, 0, stream>>>(Qb, Kb, Vb, tK, tV, tmask, outp);
}